// Round 1
// baseline (35.856 us; speedup 1.0000x reference)
//
#include <hip/hip_runtime.h>

#define NN 8192
#define MARGIN_F 1.0f
#define BLOCK 256
#define JTILE 1024

__global__ void rl_init(double* acc) {
    acc[0] = 0.0;                                   // sum
    ((unsigned long long*)acc)[1] = 0ull;           // count
}

__global__ __launch_bounds__(BLOCK) void rl_main(const float* __restrict__ preds,
                                                 const float* __restrict__ targets,
                                                 double* __restrict__ acc) {
    __shared__ float sp[JTILE];
    __shared__ float sd[JTILE];

    const int tid = threadIdx.x;
    const int i   = blockIdx.x * BLOCK + tid;
    const int j0  = blockIdx.y * JTILE;

    // cooperative stage of the j-tile (preds + durations)
    for (int k = tid; k < JTILE; k += BLOCK) {
        sp[k] = preds[j0 + k];
        sd[k] = targets[2 * (j0 + k)];      // durations interleaved at even idx
    }
    __syncthreads();

    const float pi = preds[i];
    const float di = targets[2 * i];
    const float ei = targets[2 * i + 1];

    float        fsum = 0.0f;
    unsigned int cnt  = 0u;

    if (ei == 1.0f) {
        const float a = MARGIN_F - pi;
        #pragma unroll 8
        for (int k = 0; k < JTILE; ++k) {
            const float dj  = sd[k];
            const float pen = fmaxf(a + sp[k], 0.0f);
            const bool  m   = di < dj;
            fsum += m ? pen : 0.0f;
            cnt  += m ? 1u : 0u;
        }
    }

    // wave-level reduce (64 lanes)
    #pragma unroll
    for (int off = 32; off > 0; off >>= 1) {
        fsum += __shfl_down(fsum, off);
        cnt  += __shfl_down(cnt,  off);
    }

    __shared__ float        wsum[BLOCK / 64];
    __shared__ unsigned int wcnt[BLOCK / 64];
    const int wave = tid >> 6;
    const int lane = tid & 63;
    if (lane == 0) { wsum[wave] = fsum; wcnt[wave] = cnt; }
    __syncthreads();

    if (tid == 0) {
        float        s = 0.0f;
        unsigned int c = 0u;
        #pragma unroll
        for (int w = 0; w < BLOCK / 64; ++w) { s += wsum[w]; c += wcnt[w]; }
        atomicAdd(acc, (double)s);
        atomicAdd((unsigned long long*)(acc + 1), (unsigned long long)c);
    }
}

__global__ void rl_fin(const double* __restrict__ acc, float* __restrict__ out) {
    const double             s = acc[0];
    const unsigned long long c = ((const unsigned long long*)acc)[1];
    out[0] = (c > 0ull) ? (float)(s / (double)c) : 0.0f;
}

extern "C" void kernel_launch(void* const* d_in, const int* in_sizes, int n_in,
                              void* d_out, int out_size, void* d_ws, size_t ws_size,
                              hipStream_t stream) {
    const float* preds   = (const float*)d_in[0];
    const float* targets = (const float*)d_in[1];
    float*       out     = (float*)d_out;
    double*      acc     = (double*)d_ws;   // [0]=sum (double), [1]=count (ull)

    rl_init<<<1, 1, 0, stream>>>(acc);

    dim3 grid(NN / BLOCK, NN / JTILE);      // (32, 8) = 256 blocks
    rl_main<<<grid, BLOCK, 0, stream>>>(preds, targets, acc);

    rl_fin<<<1, 1, 0, stream>>>(acc, out);
}

// Round 2
// 16.331 us; speedup vs baseline: 2.1956x; 2.1956x over previous
//
#include <hip/hip_runtime.h>

#define NN 8192
#define MARGIN_F 1.0f
#define BLOCK 256
#define ITILE 256
#define NBLK ((NN / BLOCK) * (NN / ITILE))   // 32*32 = 1024 partials

// Block (bx, by): threads own j in [bx*BLOCK, ...), i-tile [by*ITILE, ...) is
// event-compacted into LDS. Each block writes one (sum, cnt) partial slot.
__global__ __launch_bounds__(BLOCK) void rl_main(const float* __restrict__ preds,
                                                 const float* __restrict__ targets,
                                                 float* __restrict__ psum,
                                                 unsigned* __restrict__ pcnt) {
    __shared__ float2  si[ITILE];      // {MARGIN - p_i, d_i} for event rows only
    __shared__ unsigned s_cnt;

    const int tid = threadIdx.x;
    if (tid == 0) s_cnt = 0u;
    __syncthreads();

    // --- stage + ballot-compact the i-tile (ITILE == BLOCK: one elem/thread)
    {
        const int   gi = blockIdx.y * ITILE + tid;
        const float d  = targets[2 * gi];
        const float e  = targets[2 * gi + 1];
        const bool  ev = (e == 1.0f);
        const unsigned long long bal  = __ballot(ev);
        const int                lane = tid & 63;
        const int pre = __popcll(bal & ((1ull << lane) - 1ull));
        unsigned base = 0u;
        if (lane == 0) base = atomicAdd(&s_cnt, (unsigned)__popcll(bal));
        base = __shfl(base, 0);
        if (ev) si[base + pre] = make_float2(MARGIN_F - preds[gi], d);
    }
    __syncthreads();

    const unsigned m  = s_cnt;
    const int      j  = blockIdx.x * BLOCK + tid;
    const float    pj = preds[j];
    const float    dj = targets[2 * j];

    float    f0 = 0.f, f1 = 0.f, f2 = 0.f, f3 = 0.f;
    unsigned c0 = 0u, c1 = 0u, c2 = 0u, c3 = 0u;

    unsigned k = 0;
    for (; k + 4 <= m; k += 4) {
        const float2 a0 = si[k + 0], a1 = si[k + 1];
        const float2 a2 = si[k + 2], a3 = si[k + 3];
        { const bool b = a0.y < dj; f0 += b ? fmaxf(a0.x + pj, 0.f) : 0.f; c0 += b; }
        { const bool b = a1.y < dj; f1 += b ? fmaxf(a1.x + pj, 0.f) : 0.f; c1 += b; }
        { const bool b = a2.y < dj; f2 += b ? fmaxf(a2.x + pj, 0.f) : 0.f; c2 += b; }
        { const bool b = a3.y < dj; f3 += b ? fmaxf(a3.x + pj, 0.f) : 0.f; c3 += b; }
    }
    for (; k < m; ++k) {
        const float2 a = si[k];
        const bool   b = a.y < dj;
        f0 += b ? fmaxf(a.x + pj, 0.f) : 0.f;
        c0 += b;
    }
    float    fsum = (f0 + f1) + (f2 + f3);
    unsigned cnt  = (c0 + c1) + (c2 + c3);

    // --- block reduce (wave shuffle, then LDS across waves)
    #pragma unroll
    for (int off = 32; off > 0; off >>= 1) {
        fsum += __shfl_down(fsum, off);
        cnt  += __shfl_down(cnt,  off);
    }
    __shared__ float    wsum[BLOCK / 64];
    __shared__ unsigned wcnt[BLOCK / 64];
    const int wave = tid >> 6;
    const int lane = tid & 63;
    if (lane == 0) { wsum[wave] = fsum; wcnt[wave] = cnt; }
    __syncthreads();

    if (tid == 0) {
        float    s = 0.f;
        unsigned c = 0u;
        #pragma unroll
        for (int w = 0; w < BLOCK / 64; ++w) { s += wsum[w]; c += wcnt[w]; }
        const int bid = blockIdx.y * gridDim.x + blockIdx.x;
        psum[bid] = s;          // pure overwrite: no zero-init pass needed
        pcnt[bid] = c;
    }
}

__global__ __launch_bounds__(1024) void rl_fin(const float* __restrict__ psum,
                                               const unsigned* __restrict__ pcnt,
                                               float* __restrict__ out) {
    const int tid = threadIdx.x;          // 1024 threads == NBLK partials
    double             s = (double)psum[tid];
    unsigned long long c = (unsigned long long)pcnt[tid];

    #pragma unroll
    for (int off = 32; off > 0; off >>= 1) {
        s += __shfl_down(s, off);
        c += __shfl_down(c, off);
    }
    __shared__ double             ds[16];
    __shared__ unsigned long long cs[16];
    const int wave = tid >> 6;
    const int lane = tid & 63;
    if (lane == 0) { ds[wave] = s; cs[wave] = c; }
    __syncthreads();

    if (tid == 0) {
        double             S = 0.0;
        unsigned long long C = 0ull;
        #pragma unroll
        for (int w = 0; w < 16; ++w) { S += ds[w]; C += cs[w]; }
        out[0] = (C > 0ull) ? (float)(S / (double)C) : 0.0f;
    }
}

extern "C" void kernel_launch(void* const* d_in, const int* in_sizes, int n_in,
                              void* d_out, int out_size, void* d_ws, size_t ws_size,
                              hipStream_t stream) {
    const float* preds   = (const float*)d_in[0];
    const float* targets = (const float*)d_in[1];
    float*       out     = (float*)d_out;

    float*    psum = (float*)d_ws;
    unsigned* pcnt = (unsigned*)((char*)d_ws + NBLK * sizeof(float));

    dim3 grid(NN / BLOCK, NN / ITILE);    // (32, 32) = 1024 blocks
    rl_main<<<grid, BLOCK, 0, stream>>>(preds, targets, psum, pcnt);
    rl_fin<<<1, 1024, 0, stream>>>(psum, pcnt, out);
}

// Round 3
// 14.172 us; speedup vs baseline: 2.5301x; 1.1524x over previous
//
#include <hip/hip_runtime.h>

#define NN 8192
#define MARGIN_F 1.0f
#define BLOCK 256
#define JPT 2                       // j's per thread (share one LDS read)
#define ITILE 64                    // i-tile = one wave: ballot compaction, no atomics
#define GX (NN / (BLOCK * JPT))     // 16
#define GY (NN / ITILE)             // 128
#define NBLK (GX * GY)              // 2048 partials

__global__ __launch_bounds__(BLOCK) void rl_main(const float* __restrict__ preds,
                                                 const float* __restrict__ targets,
                                                 float* __restrict__ psum,
                                                 unsigned* __restrict__ pcnt) {
    __shared__ float2   si[ITILE];   // {MARGIN - p_i, d_i}, event rows only
    __shared__ unsigned s_cnt;

    const int tid = threadIdx.x;

    // --- single-wave stage + ballot-compact of the i-tile
    if (tid < 64) {
        const int   gi = blockIdx.y * ITILE + tid;
        const float d  = targets[2 * gi];
        const float e  = targets[2 * gi + 1];
        const bool  ev = (e == 1.0f);
        const unsigned long long bal = __ballot(ev);
        const int pre = __popcll(bal & ((1ull << tid) - 1ull));
        if (ev) si[pre] = make_float2(MARGIN_F - preds[gi], d);
        if (tid == 0) s_cnt = (unsigned)__popcll(bal);
    }
    __syncthreads();

    const unsigned m = s_cnt;

    const int   j1  = blockIdx.x * (BLOCK * JPT) + tid;
    const int   j2  = j1 + BLOCK;
    const float pj1 = preds[j1],        pj2 = preds[j2];
    const float dj1 = targets[2 * j1],  dj2 = targets[2 * j2];

    float    f1 = 0.f, f2 = 0.f;
    unsigned c1 = 0u,  c2 = 0u;

    #pragma unroll 4
    for (unsigned k = 0; k < m; ++k) {
        const float2 a  = si[k];
        const bool   b1 = a.y < dj1;
        const bool   b2 = a.y < dj2;
        f1 += b1 ? fmaxf(a.x + pj1, 0.f) : 0.f;
        f2 += b2 ? fmaxf(a.x + pj2, 0.f) : 0.f;
        c1 += b1;
        c2 += b2;
    }
    float    fsum = f1 + f2;
    unsigned cnt  = c1 + c2;

    // --- block reduce
    #pragma unroll
    for (int off = 32; off > 0; off >>= 1) {
        fsum += __shfl_down(fsum, off);
        cnt  += __shfl_down(cnt,  off);
    }
    __shared__ float    wsum[BLOCK / 64];
    __shared__ unsigned wcnt[BLOCK / 64];
    const int wave = tid >> 6;
    const int lane = tid & 63;
    if (lane == 0) { wsum[wave] = fsum; wcnt[wave] = cnt; }
    __syncthreads();

    if (tid == 0) {
        float    s = 0.f;
        unsigned c = 0u;
        #pragma unroll
        for (int w = 0; w < BLOCK / 64; ++w) { s += wsum[w]; c += wcnt[w]; }
        const int bid = blockIdx.y * gridDim.x + blockIdx.x;
        psum[bid] = s;          // pure overwrite: no zero-init needed
        pcnt[bid] = c;
    }
}

__global__ __launch_bounds__(1024) void rl_fin(const float* __restrict__ psum,
                                               const unsigned* __restrict__ pcnt,
                                               float* __restrict__ out) {
    const int tid = threadIdx.x;              // 1024 threads, 2 partials each
    double             s = (double)psum[tid] + (double)psum[tid + 1024];
    unsigned long long c = (unsigned long long)pcnt[tid] +
                           (unsigned long long)pcnt[tid + 1024];

    #pragma unroll
    for (int off = 32; off > 0; off >>= 1) {
        s += __shfl_down(s, off);
        c += __shfl_down(c, off);
    }
    __shared__ double             ds[16];
    __shared__ unsigned long long cs[16];
    const int wave = tid >> 6;
    const int lane = tid & 63;
    if (lane == 0) { ds[wave] = s; cs[wave] = c; }
    __syncthreads();

    if (tid == 0) {
        double             S = 0.0;
        unsigned long long C = 0ull;
        #pragma unroll
        for (int w = 0; w < 16; ++w) { S += ds[w]; C += cs[w]; }
        out[0] = (C > 0ull) ? (float)(S / (double)C) : 0.0f;
    }
}

extern "C" void kernel_launch(void* const* d_in, const int* in_sizes, int n_in,
                              void* d_out, int out_size, void* d_ws, size_t ws_size,
                              hipStream_t stream) {
    const float* preds   = (const float*)d_in[0];
    const float* targets = (const float*)d_in[1];
    float*       out     = (float*)d_out;

    float*    psum = (float*)d_ws;
    unsigned* pcnt = (unsigned*)((char*)d_ws + NBLK * sizeof(float));

    dim3 grid(GX, GY);                  // (16, 128) = 2048 blocks
    rl_main<<<grid, BLOCK, 0, stream>>>(preds, targets, psum, pcnt);
    rl_fin<<<1, 1024, 0, stream>>>(psum, pcnt, out);
}